// Round 8
// baseline (272.513 us; speedup 1.0000x reference)
//
#include <hip/hip_runtime.h>

// Problem constants
#define Bc 2
#define Sc 1024
#define Dc 1024
#define Hc 2048
#define Ec 8
#define Kc 2
#define Tc (Bc*Sc)      // 2048 tokens
#define Pc (Tc*Kc)      // 4096 jobs
#define PADROWS 128     // tile-overrun padding for hidden
#define MAXTILES 40     // sum_e ceil(cnt_e/128) <= 4096/128 + 8 = 40

typedef __bf16 bf16x8 __attribute__((ext_vector_type(8)));
typedef __bf16 bf16x4_t __attribute__((ext_vector_type(4)));
typedef float floatx4 __attribute__((ext_vector_type(4)));
typedef unsigned short ushort4_t __attribute__((ext_vector_type(4)));

// hardware bf16 convert (clang emits v_cvt_pk_bf16_f32 pairs; RNE)
__device__ inline ushort4_t cvt4hw(float4 v) {
    bf16x4_t b;
    b[0] = (__bf16)v.x; b[1] = (__bf16)v.y; b[2] = (__bf16)v.z; b[3] = (__bf16)v.w;
    return __builtin_bit_cast(ushort4_t, b);
}

// flax nn.gelu approximate=True: 0.5v(1+tanh(y)) == v * sigmoid(2y)
__device__ inline float gelu_fast(float v) {
    float z = 1.5957691216057308f * (v + 0.044715f * v * v * v);  // 2y
    return v / (1.0f + __expf(-z));
}

// async global->LDS, 16B per lane; LDS dest = wave-uniform base + lane*16
__device__ inline void gload_lds16(const void* g, void* l) {
    __builtin_amdgcn_global_load_lds((const __attribute__((address_space(1))) unsigned int*)g,
                                     (__attribute__((address_space(3))) unsigned int*)l,
                                     16, 0, 0);
}

// ---------- fused prep: bucket (block 0) + out-zero + x->bf16 + keys->bf16 ----------
#define ZERO_BLOCKS 2048
#define XCV_BLOCKS 256
#define KCV_BLOCKS 2048
#define PREP_BLOCKS (1 + ZERO_BLOCKS + XCV_BLOCKS + KCV_BLOCKS)

__global__ __launch_bounds__(256) void prep_kernel(
    const int* __restrict__ idx, const float* __restrict__ wts,
    int* __restrict__ counts, int* __restrict__ offs,
    int* __restrict__ tile_e, int* __restrict__ tile_m0,
    int* __restrict__ n_tiles,
    int* __restrict__ job_token, float* __restrict__ job_w,
    const float* __restrict__ x, unsigned short* __restrict__ Xb,
    const float* __restrict__ keys, unsigned short* __restrict__ keysb,
    float* __restrict__ out)
{
    int b = blockIdx.x, t = threadIdx.x;
    if (b == 0) {
        // ---- bucketing ----
        __shared__ int lc[Ec], lf[Ec], lo[Ec];
        if (t < Ec) { lc[t] = 0; lf[t] = 0; }
        __syncthreads();
        int myid[Pc / 256];
#pragma unroll
        for (int j = 0; j < Pc / 256; j++) {
            int i = t + j * 256;
            myid[j] = idx[i];
            atomicAdd(&lc[myid[j]], 1);
        }
        __syncthreads();
        if (t == 0) {
            int s = 0, tt = 0;
            for (int e = 0; e < Ec; e++) {
                lo[e] = s; offs[e] = s; counts[e] = lc[e];
                for (int m0 = 0; m0 < lc[e]; m0 += 128) { tile_e[tt] = e; tile_m0[tt] = m0; tt++; }
                s += lc[e];
            }
            offs[Ec] = s;
            *n_tiles = tt;
        }
        __syncthreads();
#pragma unroll
        for (int j = 0; j < Pc / 256; j++) {
            int i = t + j * 256;
            int e = myid[j];
            int pos = lo[e] + atomicAdd(&lf[e], 1);
            job_token[pos] = i >> 1;          // i = token*K + k
            job_w[pos] = wts[i];
        }
    } else if (b < 1 + ZERO_BLOCKS) {
        // ---- zero out ----
        int i = (b - 1) * 256 + t;
        ((float4*)out)[i] = (float4){0.f, 0.f, 0.f, 0.f};
    } else if (b < 1 + ZERO_BLOCKS + XCV_BLOCKS) {
        // ---- x convert (token order, unit-stride, ILP 8) ----
        const float4* src = (const float4*)x;
        ushort4_t* dst = (ushort4_t*)Xb;
        size_t i0 = (size_t)(b - 1 - ZERO_BLOCKS) * 256 + t;
        const size_t stride = (size_t)XCV_BLOCKS * 256;
        float4 v0 = src[i0 + 0 * stride];
        float4 v1 = src[i0 + 1 * stride];
        float4 v2 = src[i0 + 2 * stride];
        float4 v3 = src[i0 + 3 * stride];
        float4 v4 = src[i0 + 4 * stride];
        float4 v5 = src[i0 + 5 * stride];
        float4 v6 = src[i0 + 6 * stride];
        float4 v7 = src[i0 + 7 * stride];
        dst[i0 + 0 * stride] = cvt4hw(v0);
        dst[i0 + 1 * stride] = cvt4hw(v1);
        dst[i0 + 2 * stride] = cvt4hw(v2);
        dst[i0 + 3 * stride] = cvt4hw(v3);
        dst[i0 + 4 * stride] = cvt4hw(v4);
        dst[i0 + 5 * stride] = cvt4hw(v5);
        dst[i0 + 6 * stride] = cvt4hw(v6);
        dst[i0 + 7 * stride] = cvt4hw(v7);
    } else {
        // ---- keys convert (unit-stride, ILP 8) ----
        const float4* src = (const float4*)keys;
        ushort4_t* dst = (ushort4_t*)keysb;
        size_t i0 = (size_t)(b - 1 - ZERO_BLOCKS - XCV_BLOCKS) * 256 + t;
        const size_t stride = (size_t)KCV_BLOCKS * 256;
        float4 v0 = src[i0 + 0 * stride];
        float4 v1 = src[i0 + 1 * stride];
        float4 v2 = src[i0 + 2 * stride];
        float4 v3 = src[i0 + 3 * stride];
        float4 v4 = src[i0 + 4 * stride];
        float4 v5 = src[i0 + 5 * stride];
        float4 v6 = src[i0 + 6 * stride];
        float4 v7 = src[i0 + 7 * stride];
        dst[i0 + 0 * stride] = cvt4hw(v0);
        dst[i0 + 1 * stride] = cvt4hw(v1);
        dst[i0 + 2 * stride] = cvt4hw(v2);
        dst[i0 + 3 * stride] = cvt4hw(v3);
        dst[i0 + 4 * stride] = cvt4hw(v4);
        dst[i0 + 5 * stride] = cvt4hw(v5);
        dst[i0 + 6 * stride] = cvt4hw(v6);
        dst[i0 + 7 * stride] = cvt4hw(v7);
    }
}

// ---------- GEMM tile config ----------
#define BM 128
#define BN 128
#define BK 64
// LDS tile: 128 rows x 64 bf16 (128B = 8 chunks of 16B per row).
// Physical chunk position = logical_chunk ^ (row & 7)  (bank-conflict swizzle).
// global_load_lds: lane -> row = base+(lane>>3), phys chunk = lane&7, so lane
// fetches global logical chunk (lane&7)^(row&7). 8x128B segments per inst.

__device__ inline void stage_rows128(const unsigned short* __restrict__ g0, size_t ld, int kk,
                                     unsigned short* lds, int w, int lane) {
    int rr = lane >> 3, cp = lane & 7;
#pragma unroll
    for (int j = 0; j < 4; j++) {
        int row = w * 32 + j * 8 + rr;
        int cl = cp ^ (row & 7);
        const char* g = (const char*)(g0 + (size_t)row * ld + kk + cl * 8);
        char* l = (char*)lds + (size_t)(w * 32 + j * 8) * 128;
        gload_lds16(g, l);
    }
}

// A-panel gather-stage: same LDS layout, per-row global base from token
__device__ inline void stage_A_gather(const unsigned short* __restrict__ Xb,
                                      const int tokA[4], int kk,
                                      unsigned short* lds, int w, int lane) {
    int rr = lane >> 3, cp = lane & 7;
#pragma unroll
    for (int j = 0; j < 4; j++) {
        int row = w * 32 + j * 8 + rr;
        int cl = cp ^ (row & 7);
        const unsigned short* g = Xb + (size_t)tokA[j] * Dc + kk + cl * 8;
        char* l = (char*)lds + (size_t)(w * 32 + j * 8) * 128;
        gload_lds16(g, l);
    }
}

// GEMM1: hidden[m, n] = gelu( sum_d Xb[tok(m),d] * keys[e][n,d] ),  K=1024, N=2048
// z=0: 128x128-tile GEMM (16 x-blocks x 40 tiles), XCD-swizzled block mapping
// z=1: values fp32->bf16 convert rider (grid-stride) -- rides gemm1's idle BW
__global__ __launch_bounds__(256, 2) void gemm1_kernel(
    const unsigned short* __restrict__ Xb,      // [Tc, 1024] bf16 (token order)
    const unsigned short* __restrict__ keysb,   // [E, 2048, 1024] bf16
    const int* __restrict__ counts, const int* __restrict__ offs,
    const int* __restrict__ tile_e, const int* __restrict__ tile_m0,
    const int* __restrict__ n_tiles,
    const int* __restrict__ job_token,
    unsigned short* __restrict__ hidden,        // [Pc+PADROWS, 2048] bf16
    const float* __restrict__ values, unsigned short* __restrict__ valsb)
{
    if (blockIdx.z == 1) {
        const float4* src = (const float4*)values;
        ushort4_t* dst = (ushort4_t*)valsb;
        const size_t NF4 = (size_t)Ec * Dc * Hc / 4;
        size_t gtid = ((size_t)blockIdx.y * gridDim.x + blockIdx.x) * 256 + threadIdx.x;
        const size_t gstride = (size_t)gridDim.x * MAXTILES * 256;
#pragma unroll 4
        for (size_t i = gtid; i < NF4; i += gstride) {
            float4 v = src[i];
            dst[i] = cvt4hw(v);
        }
        return;
    }
    // XCD-aware bijective swizzle over the 16x40 z=0 plane (nwg=640, 640%8==0):
    // contiguous swizzled ids land on one XCD -> same-ty blocks share that L2.
    int lin = blockIdx.x + 16 * blockIdx.y;     // 0..639
    int swz = (lin & 7) * 80 + (lin >> 3);
    int bx = swz & 15;
    int ty = swz >> 4;
    if (ty >= *n_tiles) return;
    int e = tile_e[ty], m0 = tile_m0[ty];
    int cnt = counts[e], moff = offs[e];
    int n0 = bx * BN;
    const unsigned short* Bg = keysb + (size_t)e * Hc * Dc + (size_t)n0 * Dc;

    __shared__ unsigned short As[BM * BK];
    __shared__ unsigned short Bs[BN * BK];

    int t = threadIdx.x;
    int lane = t & 63, w = t >> 6;
    int Mq = (w & 1) * 64, Nq = (w >> 1) * 64;
    int l15 = lane & 15, l4 = lane >> 4;
    int rx = l15 & 7;   // row-dependent swizzle factor for fragment reads

    // per-thread tokens for the 4 rows this thread stages (clamped for pad rows)
    int rr8 = lane >> 3;
    int tokA[4];
#pragma unroll
    for (int j = 0; j < 4; j++) {
        int row = w * 32 + j * 8 + rr8;
        int gm = m0 + row;
        int job = moff + (gm < cnt ? gm : cnt - 1);
        tokA[j] = job_token[job];
    }

    floatx4 acc[4][4];
#pragma unroll
    for (int i = 0; i < 4; i++)
#pragma unroll
        for (int j = 0; j < 4; j++) acc[i][j] = (floatx4){0.f, 0.f, 0.f, 0.f};

    for (int kk = 0; kk < Dc; kk += BK) {
        __syncthreads();
        stage_A_gather(Xb, tokA, kk, As, w, lane);
        stage_rows128(Bg, Dc, kk, Bs, w, lane);
        __syncthreads();
#pragma unroll
        for (int s = 0; s < 2; s++) {
            bf16x8 af[4], bfr[4];
#pragma unroll
            for (int mi = 0; mi < 4; mi++)
                af[mi] = *(const bf16x8*)(As + (Mq + mi * 16 + l15) * BK + (((s * 4 + l4) ^ rx) * 8));
#pragma unroll
            for (int ni = 0; ni < 4; ni++)
                bfr[ni] = *(const bf16x8*)(Bs + (Nq + ni * 16 + l15) * BK + (((s * 4 + l4) ^ rx) * 8));
#pragma unroll
            for (int mi = 0; mi < 4; mi++)
#pragma unroll
                for (int ni = 0; ni < 4; ni++)
                    acc[mi][ni] = __builtin_amdgcn_mfma_f32_16x16x32_bf16(af[mi], bfr[ni], acc[mi][ni], 0, 0, 0);
        }
    }

#pragma unroll
    for (int mi = 0; mi < 4; mi++) {
#pragma unroll
        for (int r = 0; r < 4; r++) {
            int mloc = Mq + mi * 16 + l4 * 4 + r;
            int gm = m0 + mloc;
            if (gm < cnt) {
                size_t rowbase = (size_t)(moff + gm) * Hc + n0;
#pragma unroll
                for (int ni = 0; ni < 4; ni++) {
                    float g = gelu_fast(acc[mi][ni][r]);
                    __bf16 h = (__bf16)g;
                    hidden[rowbase + Nq + ni * 16 + l15] = __builtin_bit_cast(unsigned short, h);
                }
            }
        }
    }
}

// GEMM2: out[token, n] += w * sum_h hidden[m,h] * values[e][n,h]
// split-K=4 (z selects K-quarter, 512 each): grid 8x40x4 = 1280 blocks
// -> 5 blocks/CU at 32KB LDS (vs 2.5 at split-K=2). XCD-swizzled mapping.
__global__ __launch_bounds__(256, 2) void gemm2_kernel(
    const unsigned short* __restrict__ hidden,  // [Pc+PADROWS, 2048] bf16
    const unsigned short* __restrict__ valsb,   // [E, 1024, 2048] bf16
    const int* __restrict__ counts, const int* __restrict__ offs,
    const int* __restrict__ tile_e, const int* __restrict__ tile_m0,
    const int* __restrict__ n_tiles,
    const int* __restrict__ job_token, const float* __restrict__ job_w,
    float* __restrict__ out)
{
    // bijective XCD swizzle over full 8x40x4 grid (nwg=1280, 1280%8==0)
    int lin = blockIdx.x + 8 * (blockIdx.y + MAXTILES * blockIdx.z);   // 0..1279
    int swz = (lin & 7) * 160 + (lin >> 3);
    int bx = swz & 7;
    int ty = (swz >> 3) % MAXTILES;
    int kz = swz / (8 * MAXTILES);
    if (ty >= *n_tiles) return;
    int e = tile_e[ty], m0 = tile_m0[ty];
    int cnt = counts[e], moff = offs[e];
    int n0 = bx * BN;
    int k_begin = kz * (Hc / 4);
    int k_end = k_begin + (Hc / 4);
    const unsigned short* Ag = hidden + (size_t)(moff + m0) * Hc;
    const unsigned short* Bg = valsb + (size_t)e * Dc * Hc + (size_t)n0 * Hc;

    __shared__ unsigned short As[BM * BK];
    __shared__ unsigned short Bs[BN * BK];

    int t = threadIdx.x;
    int lane = t & 63, w = t >> 6;
    int Mq = (w & 1) * 64, Nq = (w >> 1) * 64;
    int l15 = lane & 15, l4 = lane >> 4;
    int rx = l15 & 7;

    floatx4 acc[4][4];
#pragma unroll
    for (int i = 0; i < 4; i++)
#pragma unroll
        for (int j = 0; j < 4; j++) acc[i][j] = (floatx4){0.f, 0.f, 0.f, 0.f};

    for (int kk = k_begin; kk < k_end; kk += BK) {
        __syncthreads();
        stage_rows128(Ag, Hc, kk, As, w, lane);
        stage_rows128(Bg, Hc, kk, Bs, w, lane);
        __syncthreads();
#pragma unroll
        for (int s = 0; s < 2; s++) {
            bf16x8 af[4], bfr[4];
#pragma unroll
            for (int mi = 0; mi < 4; mi++)
                af[mi] = *(const bf16x8*)(As + (Mq + mi * 16 + l15) * BK + (((s * 4 + l4) ^ rx) * 8));
#pragma unroll
            for (int ni = 0; ni < 4; ni++)
                bfr[ni] = *(const bf16x8*)(Bs + (Nq + ni * 16 + l15) * BK + (((s * 4 + l4) ^ rx) * 8));
#pragma unroll
            for (int mi = 0; mi < 4; mi++)
#pragma unroll
                for (int ni = 0; ni < 4; ni++)
                    acc[mi][ni] = __builtin_amdgcn_mfma_f32_16x16x32_bf16(af[mi], bfr[ni], acc[mi][ni], 0, 0, 0);
        }
    }

#pragma unroll
    for (int mi = 0; mi < 4; mi++) {
#pragma unroll
        for (int r = 0; r < 4; r++) {
            int mloc = Mq + mi * 16 + l4 * 4 + r;
            int gm = m0 + mloc;
            if (gm < cnt) {
                int tok = job_token[moff + gm];
                float wgt = job_w[moff + gm];
                float* orow = out + (size_t)tok * Dc + n0;
#pragma unroll
                for (int ni = 0; ni < 4; ni++) {
                    atomicAdd(orow + Nq + ni * 16 + l15, wgt * acc[mi][ni][r]);
                }
            }
        }
    }
}

// ---------- workspace layout (bytes) ----------
// counts     @ 0        (64)
// offs       @ 64       (64)
// tile_e     @ 128      (192)
// tile_m0    @ 320      (192)
// n_tiles    @ 512      (128)
// job_token  @ 640      (16384)
// job_w      @ 17024    (16384)
// Xb         @ 33408    (2048*1024*2   = 4194304)   -> 4227712
// keysb      @ 4227712  (33554432)                  -> 37782144
// valsb      @ 37782144 (33554432)                  -> 71336576
// hidden     @ 71336576 ((4096+128)*2048*2 = 17301504) -> 88638080 total

extern "C" void kernel_launch(void* const* d_in, const int* in_sizes, int n_in,
                              void* d_out, int out_size, void* d_ws, size_t ws_size,
                              hipStream_t stream) {
    const float* x      = (const float*)d_in[0];
    const float* keys   = (const float*)d_in[1];
    const float* values = (const float*)d_in[2];
    const int*   eidx   = (const int*)d_in[3];
    const float* ew     = (const float*)d_in[4];
    float* out = (float*)d_out;
    char* ws = (char*)d_ws;

    int*   counts    = (int*)(ws + 0);
    int*   offs      = (int*)(ws + 64);
    int*   tile_e    = (int*)(ws + 128);
    int*   tile_m0   = (int*)(ws + 320);
    int*   n_tiles   = (int*)(ws + 512);
    int*   job_token = (int*)(ws + 640);
    float* job_w     = (float*)(ws + 17024);
    unsigned short* Xb     = (unsigned short*)(ws + 33408);
    unsigned short* keysb  = (unsigned short*)(ws + 4227712);
    unsigned short* valsb  = (unsigned short*)(ws + 37782144);
    unsigned short* hidden = (unsigned short*)(ws + 71336576);

    // node 1: bucket + out-zero + x-convert + keys-convert (all independent)
    prep_kernel<<<PREP_BLOCKS, 256, 0, stream>>>(
        eidx, ew, counts, offs, tile_e, tile_m0, n_tiles, job_token, job_w,
        x, Xb, keys, keysb, out);

    // node 2: GEMM1 (+ values-convert rider on z=1)
    gemm1_kernel<<<dim3(Hc / BN, MAXTILES, 2), 256, 0, stream>>>(
        Xb, keysb, counts, offs, tile_e, tile_m0, n_tiles, job_token, hidden,
        values, valsb);

    // node 3: GEMM2 (split-K=4, XCD-swizzled)
    gemm2_kernel<<<dim3(Dc / BN, MAXTILES, 4), 256, 0, stream>>>(
        hidden, valsb, counts, offs, tile_e, tile_m0, n_tiles, job_token, job_w, out);
}

// Round 9
// 245.224 us; speedup vs baseline: 1.1113x; 1.1113x over previous
//
#include <hip/hip_runtime.h>

// Problem constants
#define Bc 2
#define Sc 1024
#define Dc 1024
#define Hc 2048
#define Ec 8
#define Kc 2
#define Tc (Bc*Sc)      // 2048 tokens
#define Pc (Tc*Kc)      // 4096 jobs
#define PADROWS 128     // tile-overrun padding for hidden
#define MAXTILES 40     // sum_e ceil(cnt_e/128) <= 4096/128 + 8 = 40

typedef __bf16 bf16x8 __attribute__((ext_vector_type(8)));
typedef __bf16 bf16x4_t __attribute__((ext_vector_type(4)));
typedef float floatx4 __attribute__((ext_vector_type(4)));
typedef unsigned short ushort4_t __attribute__((ext_vector_type(4)));

// hardware bf16 convert (clang emits v_cvt_pk_bf16_f32 pairs; RNE)
__device__ inline ushort4_t cvt4hw(float4 v) {
    bf16x4_t b;
    b[0] = (__bf16)v.x; b[1] = (__bf16)v.y; b[2] = (__bf16)v.z; b[3] = (__bf16)v.w;
    return __builtin_bit_cast(ushort4_t, b);
}

// flax nn.gelu approximate=True: 0.5v(1+tanh(y)) == v * sigmoid(2y)
__device__ inline float gelu_fast(float v) {
    float z = 1.5957691216057308f * (v + 0.044715f * v * v * v);  // 2y
    return v / (1.0f + __expf(-z));
}

// async global->LDS, 16B per lane; LDS dest = wave-uniform base + lane*16
__device__ inline void gload_lds16(const void* g, void* l) {
    __builtin_amdgcn_global_load_lds((const __attribute__((address_space(1))) unsigned int*)g,
                                     (__attribute__((address_space(3))) unsigned int*)l,
                                     16, 0, 0);
}

// ---------- fused prep: bucket (block 0) + out-zero + x->bf16 + keys->bf16 ----------
#define ZERO_BLOCKS 2048
#define XCV_BLOCKS 256
#define KCV_BLOCKS 2048
#define PREP_BLOCKS (1 + ZERO_BLOCKS + XCV_BLOCKS + KCV_BLOCKS)

__global__ __launch_bounds__(256) void prep_kernel(
    const int* __restrict__ idx, const float* __restrict__ wts,
    int* __restrict__ counts, int* __restrict__ offs,
    int* __restrict__ tile_e, int* __restrict__ tile_m0,
    int* __restrict__ n_tiles,
    int* __restrict__ job_token, float* __restrict__ job_w,
    const float* __restrict__ x, unsigned short* __restrict__ Xb,
    const float* __restrict__ keys, unsigned short* __restrict__ keysb,
    float* __restrict__ out)
{
    int b = blockIdx.x, t = threadIdx.x;
    if (b == 0) {
        // ---- bucketing ----
        __shared__ int lc[Ec], lf[Ec], lo[Ec];
        if (t < Ec) { lc[t] = 0; lf[t] = 0; }
        __syncthreads();
        int myid[Pc / 256];
#pragma unroll
        for (int j = 0; j < Pc / 256; j++) {
            int i = t + j * 256;
            myid[j] = idx[i];
            atomicAdd(&lc[myid[j]], 1);
        }
        __syncthreads();
        if (t == 0) {
            int s = 0, tt = 0;
            for (int e = 0; e < Ec; e++) {
                lo[e] = s; offs[e] = s; counts[e] = lc[e];
                for (int m0 = 0; m0 < lc[e]; m0 += 128) { tile_e[tt] = e; tile_m0[tt] = m0; tt++; }
                s += lc[e];
            }
            offs[Ec] = s;
            *n_tiles = tt;
        }
        __syncthreads();
#pragma unroll
        for (int j = 0; j < Pc / 256; j++) {
            int i = t + j * 256;
            int e = myid[j];
            int pos = lo[e] + atomicAdd(&lf[e], 1);
            job_token[pos] = i >> 1;          // i = token*K + k
            job_w[pos] = wts[i];
        }
    } else if (b < 1 + ZERO_BLOCKS) {
        // ---- zero out ----
        int i = (b - 1) * 256 + t;
        ((float4*)out)[i] = (float4){0.f, 0.f, 0.f, 0.f};
    } else if (b < 1 + ZERO_BLOCKS + XCV_BLOCKS) {
        // ---- x convert (token order, unit-stride, ILP 8) ----
        const float4* src = (const float4*)x;
        ushort4_t* dst = (ushort4_t*)Xb;
        size_t i0 = (size_t)(b - 1 - ZERO_BLOCKS) * 256 + t;
        const size_t stride = (size_t)XCV_BLOCKS * 256;
        float4 v0 = src[i0 + 0 * stride];
        float4 v1 = src[i0 + 1 * stride];
        float4 v2 = src[i0 + 2 * stride];
        float4 v3 = src[i0 + 3 * stride];
        float4 v4 = src[i0 + 4 * stride];
        float4 v5 = src[i0 + 5 * stride];
        float4 v6 = src[i0 + 6 * stride];
        float4 v7 = src[i0 + 7 * stride];
        dst[i0 + 0 * stride] = cvt4hw(v0);
        dst[i0 + 1 * stride] = cvt4hw(v1);
        dst[i0 + 2 * stride] = cvt4hw(v2);
        dst[i0 + 3 * stride] = cvt4hw(v3);
        dst[i0 + 4 * stride] = cvt4hw(v4);
        dst[i0 + 5 * stride] = cvt4hw(v5);
        dst[i0 + 6 * stride] = cvt4hw(v6);
        dst[i0 + 7 * stride] = cvt4hw(v7);
    } else {
        // ---- keys convert (unit-stride, ILP 8) ----
        const float4* src = (const float4*)keys;
        ushort4_t* dst = (ushort4_t*)keysb;
        size_t i0 = (size_t)(b - 1 - ZERO_BLOCKS - XCV_BLOCKS) * 256 + t;
        const size_t stride = (size_t)KCV_BLOCKS * 256;
        float4 v0 = src[i0 + 0 * stride];
        float4 v1 = src[i0 + 1 * stride];
        float4 v2 = src[i0 + 2 * stride];
        float4 v3 = src[i0 + 3 * stride];
        float4 v4 = src[i0 + 4 * stride];
        float4 v5 = src[i0 + 5 * stride];
        float4 v6 = src[i0 + 6 * stride];
        float4 v7 = src[i0 + 7 * stride];
        dst[i0 + 0 * stride] = cvt4hw(v0);
        dst[i0 + 1 * stride] = cvt4hw(v1);
        dst[i0 + 2 * stride] = cvt4hw(v2);
        dst[i0 + 3 * stride] = cvt4hw(v3);
        dst[i0 + 4 * stride] = cvt4hw(v4);
        dst[i0 + 5 * stride] = cvt4hw(v5);
        dst[i0 + 6 * stride] = cvt4hw(v6);
        dst[i0 + 7 * stride] = cvt4hw(v7);
    }
}

// ---------- GEMM tile config ----------
#define BM 128
#define BN 128
#define BK 64
// LDS tile: 128 rows x 64 bf16 (128B = 8 chunks of 16B per row).
// Physical chunk position = logical_chunk ^ (row & 7)  (bank-conflict swizzle).
// global_load_lds: lane -> row = base+(lane>>3), phys chunk = lane&7, so lane
// fetches global logical chunk (lane&7)^(row&7). 8x128B segments per inst.

__device__ inline void stage_rows128(const unsigned short* __restrict__ g0, size_t ld, int kk,
                                     unsigned short* lds, int w, int lane) {
    int rr = lane >> 3, cp = lane & 7;
#pragma unroll
    for (int j = 0; j < 4; j++) {
        int row = w * 32 + j * 8 + rr;
        int cl = cp ^ (row & 7);
        const char* g = (const char*)(g0 + (size_t)row * ld + kk + cl * 8);
        char* l = (char*)lds + (size_t)(w * 32 + j * 8) * 128;
        gload_lds16(g, l);
    }
}

// A-panel gather-stage: same LDS layout, per-row global base from token
__device__ inline void stage_A_gather(const unsigned short* __restrict__ Xb,
                                      const int tokA[4], int kk,
                                      unsigned short* lds, int w, int lane) {
    int rr = lane >> 3, cp = lane & 7;
#pragma unroll
    for (int j = 0; j < 4; j++) {
        int row = w * 32 + j * 8 + rr;
        int cl = cp ^ (row & 7);
        const unsigned short* g = Xb + (size_t)tokA[j] * Dc + kk + cl * 8;
        char* l = (char*)lds + (size_t)(w * 32 + j * 8) * 128;
        gload_lds16(g, l);
    }
}

// GEMM1: hidden[m, n] = gelu( sum_d Xb[tok(m),d] * keys[e][n,d] ),  K=1024, N=2048
// z=0: 128x128-tile GEMM (16 x-blocks x 40 tiles), XCD-swizzled block mapping
// z=1: values fp32->bf16 convert rider (grid-stride) -- rides gemm1's idle BW
__global__ __launch_bounds__(256, 2) void gemm1_kernel(
    const unsigned short* __restrict__ Xb,      // [Tc, 1024] bf16 (token order)
    const unsigned short* __restrict__ keysb,   // [E, 2048, 1024] bf16
    const int* __restrict__ counts, const int* __restrict__ offs,
    const int* __restrict__ tile_e, const int* __restrict__ tile_m0,
    const int* __restrict__ n_tiles,
    const int* __restrict__ job_token,
    unsigned short* __restrict__ hidden,        // [Pc+PADROWS, 2048] bf16
    const float* __restrict__ values, unsigned short* __restrict__ valsb)
{
    if (blockIdx.z == 1) {
        const float4* src = (const float4*)values;
        ushort4_t* dst = (ushort4_t*)valsb;
        const size_t NF4 = (size_t)Ec * Dc * Hc / 4;
        size_t gtid = ((size_t)blockIdx.y * gridDim.x + blockIdx.x) * 256 + threadIdx.x;
        const size_t gstride = (size_t)gridDim.x * MAXTILES * 256;
#pragma unroll 4
        for (size_t i = gtid; i < NF4; i += gstride) {
            float4 v = src[i];
            dst[i] = cvt4hw(v);
        }
        return;
    }
    // XCD-aware bijective swizzle over the 16x40 z=0 plane (nwg=640, 640%8==0):
    // contiguous swizzled ids land on one XCD -> same-ty blocks share that L2.
    int lin = blockIdx.x + 16 * blockIdx.y;     // 0..639
    int swz = (lin & 7) * 80 + (lin >> 3);
    int bx = swz & 15;
    int ty = swz >> 4;
    if (ty >= *n_tiles) return;
    int e = tile_e[ty], m0 = tile_m0[ty];
    int cnt = counts[e], moff = offs[e];
    int n0 = bx * BN;
    const unsigned short* Bg = keysb + (size_t)e * Hc * Dc + (size_t)n0 * Dc;

    __shared__ unsigned short As[BM * BK];
    __shared__ unsigned short Bs[BN * BK];

    int t = threadIdx.x;
    int lane = t & 63, w = t >> 6;
    int Mq = (w & 1) * 64, Nq = (w >> 1) * 64;
    int l15 = lane & 15, l4 = lane >> 4;
    int rx = l15 & 7;   // row-dependent swizzle factor for fragment reads

    // per-thread tokens for the 4 rows this thread stages (clamped for pad rows)
    int rr8 = lane >> 3;
    int tokA[4];
#pragma unroll
    for (int j = 0; j < 4; j++) {
        int row = w * 32 + j * 8 + rr8;
        int gm = m0 + row;
        int job = moff + (gm < cnt ? gm : cnt - 1);
        tokA[j] = job_token[job];
    }

    floatx4 acc[4][4];
#pragma unroll
    for (int i = 0; i < 4; i++)
#pragma unroll
        for (int j = 0; j < 4; j++) acc[i][j] = (floatx4){0.f, 0.f, 0.f, 0.f};

    for (int kk = 0; kk < Dc; kk += BK) {
        __syncthreads();
        stage_A_gather(Xb, tokA, kk, As, w, lane);
        stage_rows128(Bg, Dc, kk, Bs, w, lane);
        __syncthreads();
#pragma unroll
        for (int s = 0; s < 2; s++) {
            bf16x8 af[4], bfr[4];
#pragma unroll
            for (int mi = 0; mi < 4; mi++)
                af[mi] = *(const bf16x8*)(As + (Mq + mi * 16 + l15) * BK + (((s * 4 + l4) ^ rx) * 8));
#pragma unroll
            for (int ni = 0; ni < 4; ni++)
                bfr[ni] = *(const bf16x8*)(Bs + (Nq + ni * 16 + l15) * BK + (((s * 4 + l4) ^ rx) * 8));
#pragma unroll
            for (int mi = 0; mi < 4; mi++)
#pragma unroll
                for (int ni = 0; ni < 4; ni++)
                    acc[mi][ni] = __builtin_amdgcn_mfma_f32_16x16x32_bf16(af[mi], bfr[ni], acc[mi][ni], 0, 0, 0);
        }
    }

#pragma unroll
    for (int mi = 0; mi < 4; mi++) {
#pragma unroll
        for (int r = 0; r < 4; r++) {
            int mloc = Mq + mi * 16 + l4 * 4 + r;
            int gm = m0 + mloc;
            if (gm < cnt) {
                size_t rowbase = (size_t)(moff + gm) * Hc + n0;
#pragma unroll
                for (int ni = 0; ni < 4; ni++) {
                    float g = gelu_fast(acc[mi][ni][r]);
                    __bf16 h = (__bf16)g;
                    hidden[rowbase + Nq + ni * 16 + l15] = __builtin_bit_cast(unsigned short, h);
                }
            }
        }
    }
}

// GEMM2: out[token, n] += w * sum_h hidden[m,h] * values[e][n,h]
// split-K=2 (z selects K-half, 1024 each): grid 8x40x2 = 640 blocks, XCD-swizzled.
__global__ __launch_bounds__(256, 2) void gemm2_kernel(
    const unsigned short* __restrict__ hidden,  // [Pc+PADROWS, 2048] bf16
    const unsigned short* __restrict__ valsb,   // [E, 1024, 2048] bf16
    const int* __restrict__ counts, const int* __restrict__ offs,
    const int* __restrict__ tile_e, const int* __restrict__ tile_m0,
    const int* __restrict__ n_tiles,
    const int* __restrict__ job_token, const float* __restrict__ job_w,
    float* __restrict__ out)
{
    // bijective XCD swizzle over full 8x40x2 grid (nwg=640, 640%8==0)
    int lin = blockIdx.x + 8 * (blockIdx.y + MAXTILES * blockIdx.z);   // 0..639
    int swz = (lin & 7) * 80 + (lin >> 3);
    int bx = swz & 7;
    int ty = (swz >> 3) % MAXTILES;
    int kz = swz / (8 * MAXTILES);
    if (ty >= *n_tiles) return;
    int e = tile_e[ty], m0 = tile_m0[ty];
    int cnt = counts[e], moff = offs[e];
    int n0 = bx * BN;
    int k_begin = kz * (Hc / 2);
    int k_end = k_begin + (Hc / 2);
    const unsigned short* Ag = hidden + (size_t)(moff + m0) * Hc;
    const unsigned short* Bg = valsb + (size_t)e * Dc * Hc + (size_t)n0 * Hc;

    __shared__ unsigned short As[BM * BK];
    __shared__ unsigned short Bs[BN * BK];

    int t = threadIdx.x;
    int lane = t & 63, w = t >> 6;
    int Mq = (w & 1) * 64, Nq = (w >> 1) * 64;
    int l15 = lane & 15, l4 = lane >> 4;
    int rx = l15 & 7;

    floatx4 acc[4][4];
#pragma unroll
    for (int i = 0; i < 4; i++)
#pragma unroll
        for (int j = 0; j < 4; j++) acc[i][j] = (floatx4){0.f, 0.f, 0.f, 0.f};

    for (int kk = k_begin; kk < k_end; kk += BK) {
        __syncthreads();
        stage_rows128(Ag, Hc, kk, As, w, lane);
        stage_rows128(Bg, Hc, kk, Bs, w, lane);
        __syncthreads();
#pragma unroll
        for (int s = 0; s < 2; s++) {
            bf16x8 af[4], bfr[4];
#pragma unroll
            for (int mi = 0; mi < 4; mi++)
                af[mi] = *(const bf16x8*)(As + (Mq + mi * 16 + l15) * BK + (((s * 4 + l4) ^ rx) * 8));
#pragma unroll
            for (int ni = 0; ni < 4; ni++)
                bfr[ni] = *(const bf16x8*)(Bs + (Nq + ni * 16 + l15) * BK + (((s * 4 + l4) ^ rx) * 8));
#pragma unroll
            for (int mi = 0; mi < 4; mi++)
#pragma unroll
                for (int ni = 0; ni < 4; ni++)
                    acc[mi][ni] = __builtin_amdgcn_mfma_f32_16x16x32_bf16(af[mi], bfr[ni], acc[mi][ni], 0, 0, 0);
        }
    }

#pragma unroll
    for (int mi = 0; mi < 4; mi++) {
#pragma unroll
        for (int r = 0; r < 4; r++) {
            int mloc = Mq + mi * 16 + l4 * 4 + r;
            int gm = m0 + mloc;
            if (gm < cnt) {
                int tok = job_token[moff + gm];
                float wgt = job_w[moff + gm];
                float* orow = out + (size_t)tok * Dc + n0;
#pragma unroll
                for (int ni = 0; ni < 4; ni++) {
                    atomicAdd(orow + Nq + ni * 16 + l15, wgt * acc[mi][ni][r]);
                }
            }
        }
    }
}

// ---------- workspace layout (bytes) ----------
// counts     @ 0        (64)
// offs       @ 64       (64)
// tile_e     @ 128      (192)
// tile_m0    @ 320      (192)
// n_tiles    @ 512      (128)
// job_token  @ 640      (16384)
// job_w      @ 17024    (16384)
// Xb         @ 33408    (2048*1024*2   = 4194304)   -> 4227712
// keysb      @ 4227712  (33554432)                  -> 37782144
// valsb      @ 37782144 (33554432)                  -> 71336576
// hidden     @ 71336576 ((4096+128)*2048*2 = 17301504) -> 88638080 total

extern "C" void kernel_launch(void* const* d_in, const int* in_sizes, int n_in,
                              void* d_out, int out_size, void* d_ws, size_t ws_size,
                              hipStream_t stream) {
    const float* x      = (const float*)d_in[0];
    const float* keys   = (const float*)d_in[1];
    const float* values = (const float*)d_in[2];
    const int*   eidx   = (const int*)d_in[3];
    const float* ew     = (const float*)d_in[4];
    float* out = (float*)d_out;
    char* ws = (char*)d_ws;

    int*   counts    = (int*)(ws + 0);
    int*   offs      = (int*)(ws + 64);
    int*   tile_e    = (int*)(ws + 128);
    int*   tile_m0   = (int*)(ws + 320);
    int*   n_tiles   = (int*)(ws + 512);
    int*   job_token = (int*)(ws + 640);
    float* job_w     = (float*)(ws + 17024);
    unsigned short* Xb     = (unsigned short*)(ws + 33408);
    unsigned short* keysb  = (unsigned short*)(ws + 4227712);
    unsigned short* valsb  = (unsigned short*)(ws + 37782144);
    unsigned short* hidden = (unsigned short*)(ws + 71336576);

    // node 1: bucket + out-zero + x-convert + keys-convert (all independent)
    prep_kernel<<<PREP_BLOCKS, 256, 0, stream>>>(
        eidx, ew, counts, offs, tile_e, tile_m0, n_tiles, job_token, job_w,
        x, Xb, keys, keysb, out);

    // node 2: GEMM1 (+ values-convert rider on z=1)
    gemm1_kernel<<<dim3(Hc / BN, MAXTILES, 2), 256, 0, stream>>>(
        Xb, keysb, counts, offs, tile_e, tile_m0, n_tiles, job_token, hidden,
        values, valsb);

    // node 3: GEMM2 (split-K=2, XCD-swizzled)
    gemm2_kernel<<<dim3(Dc / BN, MAXTILES, 2), 256, 0, stream>>>(
        hidden, valsb, counts, offs, tile_e, tile_m0, n_tiles, job_token, job_w, out);
}